// Round 1
// baseline (275.671 us; speedup 1.0000x reference)
//
#include <hip/hip_runtime.h>

// GraphPool: max-pool over self + gathered neighbor rows.
// N_PER=20000 rows per degree segment, degrees 0..10, F=128 fp32 features.
// Row r in segment d: out[r] = max(feat[r], max_j feat[adj_d[i][j]]), i = r - d*N_PER.
// Degree-0 segment is a straight copy.

#define N_PER 20000
#define NDEG 10
#define F 128
#define N_ATOMS (N_PER * (NDEG + 1))
#define ROWS_PER_BLOCK 8   // 256 threads / 32 lanes-per-row; 20000 % 8 == 0 -> uniform deg per block

struct AdjPtrs { const int* p[NDEG]; };

__global__ __launch_bounds__(256) void graphpool_kernel(
    const float* __restrict__ feat,
    AdjPtrs adj,
    float* __restrict__ out)
{
    const int row  = blockIdx.x * ROWS_PER_BLOCK + (threadIdx.x >> 5);
    const int lane = threadIdx.x & 31;          // one float4 (16B) per lane, 32 lanes = 512B row

    const int deg = row / N_PER;                // wave-uniform (blocks never straddle segments)

    float4 v = ((const float4*)(feat + (size_t)row * F))[lane];

    if (deg > 0) {
        const int i = row - deg * N_PER;
        const int* __restrict__ a = adj.p[deg - 1] + (size_t)i * deg;
        #pragma unroll 4
        for (int j = 0; j < deg; ++j) {
            const int nb = a[j];                // same addr across 32 lanes -> broadcast
            const float4 g = ((const float4*)(feat + (size_t)nb * F))[lane];
            v.x = fmaxf(v.x, g.x);
            v.y = fmaxf(v.y, g.y);
            v.z = fmaxf(v.z, g.z);
            v.w = fmaxf(v.w, g.w);
        }
    }

    ((float4*)(out + (size_t)row * F))[lane] = v;
}

extern "C" void kernel_launch(void* const* d_in, const int* in_sizes, int n_in,
                              void* d_out, int out_size, void* d_ws, size_t ws_size,
                              hipStream_t stream) {
    const float* feat = (const float*)d_in[0];
    // d_in[1] is deg_slice (unused; layout is fixed: start = deg*N_PER, count = N_PER)
    AdjPtrs adj;
    for (int d = 0; d < NDEG; ++d) adj.p[d] = (const int*)d_in[2 + d];
    float* out = (float*)d_out;

    const int grid = N_ATOMS / ROWS_PER_BLOCK;  // 27500 blocks, exact
    graphpool_kernel<<<grid, 256, 0, stream>>>(feat, adj, out);
}